// Round 6
// baseline (468.944 us; speedup 1.0000x reference)
//
#include <hip/hip_runtime.h>

// Problem: T=2048, B=16, N=2048, binary fp32 spikes, duration=100.
// out[t,b,n] = 1 if any spike in window [t-duration+1, t], else 0.
//
// R0-R5 post-mortem: the time-scan column-walk (512B-2KB bursts at 128KB
// stride, mixed R/W) is pattern-limited at ~2.7 TB/s regardless of ILP
// (R5: 8 asm loads in flight) or occupancy (R4: 74%). Contiguous streams
// on this box run 6.3-6.4 TB/s. Since the data is binary, restructure
// into three pure contiguous streams via a packed bitmask:
//   1) binarize:  256MB linear read  -> 8MB bitmask      (~read roofline)
//   2) window_or: word-parallel sliding OR over t, doubling-tree in LDS;
//                 touches ~16MB, L2/L3-resident           (~few us)
//   3) expand:    8MB words -> 256MB linear NT writes     (~write roofline)
// Same total HBM traffic as before, all of it at contiguous-stream rate.
// Falls back to the verified single-pass scan if ws_size < 16MB.

#define T_TOTAL 2048
#define B_DIM   16
#define N_DIM   2048
#define M_COLS  (B_DIM * N_DIM)        // 32768 floats per t-row
#define MW      (M_COLS / 32)          // 1024 words per t-row
#define BM_WORDS ((long long)T_TOTAL * MW)
#define BM_BYTES (BM_WORDS * 4)        // 8 MiB

typedef float v4f __attribute__((ext_vector_type(4)));

// ---------------- Phase 1: binarize to bitmask ----------------
// thread: 8 consecutive floats -> byte; 4-lane shfl_xor pack -> u32 word.
__global__ __launch_bounds__(256) void binarize_kernel(
    const float* __restrict__ x, unsigned* __restrict__ bm)
{
    const long long total8 = (long long)T_TOTAL * M_COLS / 8;
    const int gid = blockIdx.x * blockDim.x + threadIdx.x;
    const int gsz = gridDim.x * blockDim.x;       // multiple of 4
    for (long long g = gid; g < total8; g += gsz) {
        const v4f* p = (const v4f*)(x + g * 8);
        v4f a = p[0], b = p[1];
        unsigned byte =
            (a.x != 0.f ?   1u : 0u) | (a.y != 0.f ?   2u : 0u) |
            (a.z != 0.f ?   4u : 0u) | (a.w != 0.f ?   8u : 0u) |
            (b.x != 0.f ?  16u : 0u) | (b.y != 0.f ?  32u : 0u) |
            (b.z != 0.f ?  64u : 0u) | (b.w != 0.f ? 128u : 0u);
        unsigned my = byte << (8 * (threadIdx.x & 3));
        my |= __shfl_xor(my, 1);
        my |= __shfl_xor(my, 2);
        if ((threadIdx.x & 3) == 0) bm[g >> 2] = my;   // g%4 == tid%4
    }
}

// ---------------- Phase 2: sliding-window OR along t ----------------
// Block tile: 32 word-columns x 128 output rows (+104 halo rows).
// Doubling tree (ping-pong LDS): spans 2,4,8,16,32,64; then exact-window
// combine. Valid for 65 <= dur <= 104 via O64 taps, 33..64 via O32 taps,
// else brute-force from global bm (correct, slow; never hit at dur=100).
#define TCHUNK 128
#define HALO   104
#define ROWS   (TCHUNK + HALO)   // 232
#define WTILE  32

__global__ __launch_bounds__(256) void window_or_kernel(
    const unsigned* __restrict__ bm, unsigned* __restrict__ obm,
    const int* __restrict__ dur_p)
{
    __shared__ unsigned A[ROWS][WTILE];
    __shared__ unsigned Bf[ROWS][WTILE];
    const int w0  = blockIdx.x * WTILE;
    const int t0  = blockIdx.y * TCHUNK;
    const int dur = dur_p[0];

    // load (zero-fill t<0)
    for (int idx = threadIdx.x; idx < ROWS * WTILE; idx += 256) {
        const int lr = idx / WTILE, w = idx % WTILE;
        const int tg = t0 - HALO + lr;
        A[lr][w] = (tg >= 0) ? bm[(long long)tg * MW + w0 + w] : 0u;
    }
    __syncthreads();

#define LEVEL(SRC, DST, D)                                            \
    for (int idx = threadIdx.x; idx < ROWS * WTILE; idx += 256) {     \
        const int lr = idx / WTILE, w = idx % WTILE;                  \
        unsigned v = SRC[lr][w];                                      \
        if (lr >= D) v |= SRC[lr - D][w];                             \
        DST[lr][w] = v;                                               \
    }                                                                 \
    __syncthreads();

    LEVEL(A, Bf, 1)    // O2
    LEVEL(Bf, A, 2)    // O4
    LEVEL(A, Bf, 4)    // O8
    LEVEL(Bf, A, 8)    // O16
    LEVEL(A, Bf, 16)   // O32  (kept in Bf)
    LEVEL(Bf, A, 32)   // O64  (in A)
#undef LEVEL

    for (int idx = threadIdx.x; idx < TCHUNK * WTILE; idx += 256) {
        const int r = idx / WTILE, w = idx % WTILE;
        const int lr = HALO + r;
        unsigned v;
        if (dur >= 65) {                 // 65..104: two O64 taps
            v = A[lr][w] | A[lr - (dur - 64)][w];
        } else if (dur >= 33) {          // 33..64: two O32 taps
            v = Bf[lr][w] | Bf[lr - (dur - 32)][w];
        } else {                         // tiny dur: brute force (correct path)
            v = 0u;
            const int tg = t0 + r;
            for (int k = 0; k < dur && k <= tg; ++k)
                v |= bm[(long long)(tg - k) * MW + w0 + w];
        }
        obm[(long long)(t0 + r) * MW + w0 + w] = v;
    }
}

// ---------------- Phase 3: expand bits to floats, linear NT stores ----------------
__global__ __launch_bounds__(256) void expand_kernel(
    const unsigned* __restrict__ obm, float* __restrict__ out)
{
    const long long total4 = (long long)T_TOTAL * M_COLS / 4;
    const int gid = blockIdx.x * blockDim.x + threadIdx.x;
    const int gsz = gridDim.x * blockDim.x;
    for (long long q = gid; q < total4; q += gsz) {
        const unsigned word = obm[q >> 3];
        const unsigned b = (word >> ((q & 7) * 4)) & 0xFu;
        v4f o;
        o.x = (b & 1u) ? 1.f : 0.f;
        o.y = (b & 2u) ? 1.f : 0.f;
        o.z = (b & 4u) ? 1.f : 0.f;
        o.w = (b & 8u) ? 1.f : 0.f;
        __builtin_nontemporal_store(o, (v4f*)out + q);
    }
}

// ---------------- Fallback: verified single-pass scan (R0) ----------------
#define FCHUNK 256
__global__ __launch_bounds__(256) void psp_scan_fallback(
    const float* __restrict__ x, const int* __restrict__ dur_p,
    float* __restrict__ out)
{
    const int col = blockIdx.x * blockDim.x + threadIdx.x;
    const int t0  = blockIdx.y * FCHUNK;
    const int duration = dur_p[0];
    int last = t0 - duration;
    int tstart = t0 - duration + 1;
    if (tstart < 0) tstart = 0;
    const float* xc = x + col;
    float* oc = out + col;
    for (int t = tstart; t < t0; ++t)
        if (xc[t * M_COLS] != 0.0f) last = t;
    #pragma unroll 4
    for (int t = t0; t < t0 + FCHUNK; ++t) {
        if (xc[t * M_COLS] != 0.0f) last = t;
        oc[t * M_COLS] = (t - last < duration) ? 1.0f : 0.0f;
    }
}

extern "C" void kernel_launch(void* const* d_in, const int* in_sizes, int n_in,
                              void* d_out, int out_size, void* d_ws, size_t ws_size,
                              hipStream_t stream) {
    const float* x     = (const float*)d_in[0];
    const int*   dur_p = (const int*)d_in[1];
    float*       out   = (float*)d_out;

    if (d_ws != nullptr && ws_size >= (size_t)(2 * BM_BYTES)) {
        unsigned* bm  = (unsigned*)d_ws;
        unsigned* obm = bm + BM_WORDS;
        binarize_kernel<<<dim3(2048), dim3(256), 0, stream>>>(x, bm);
        window_or_kernel<<<dim3(MW / WTILE, T_TOTAL / TCHUNK), dim3(256), 0, stream>>>(bm, obm, dur_p);
        expand_kernel<<<dim3(2048), dim3(256), 0, stream>>>(obm, out);
    } else {
        dim3 grid(M_COLS / 256, T_TOTAL / FCHUNK);
        psp_scan_fallback<<<grid, dim3(256), 0, stream>>>(x, dur_p, out);
    }
}